// Round 16
// baseline (382.722 us; speedup 1.0000x reference)
//
#include <hip/hip_runtime.h>
#include <hip/hip_bf16.h>

// ---------------------------------------------------------------------------
// GATv2 x2 (PyG GATv2Conv semantics with self-loops), MI355X.
// R16: R13 (proven 243us, NT hints dropped as null) + degree-sorted node
// permutation for agg1/agg2 wave load-balance (counting sort by degree,
// folded into the CSR scan kernels + 1 tiny scatter dispatch).
// ---------------------------------------------------------------------------

typedef unsigned short u16;
typedef short bf16x8 __attribute__((ext_vector_type(8)));
typedef float f32x4 __attribute__((ext_vector_type(4)));
typedef float f32x2 __attribute__((ext_vector_type(2)));

#define F_IN   128
#define CH     32
#define H1     8
#define JT1    512   // 2 * H1*CH  (xl | xr concatenated)
#define JH1    256   // H1*CH
#define JT2    64    // 2 * CH
#define JH2    32

// ---- ws layout (bytes) ----------------------------------------------------
#define OFF_Y1     0UL
#define OFF_H      52000000UL
#define OFF_Y2     78000000UL
#define OFF_COL    85000000UL     // 850k*4 = 3.4MB -> ends 88.4M
#define OFF_PERM   88400000UL     // 50k*4 = 200KB -> ends 88.6M
#define OFF_DEG    89000000UL     // 200KB -> ends 89.2M
#define OFF_DH     89200000UL     // 1KB bucket histogram
#define OFF_DCUR   89201024UL     // 1KB bucket cursors
#define OFF_ROW    89400000UL
#define OFF_CUR    89800000UL
#define OFF_WC     90200000UL
#define OFF_FLAG   90600000UL
#define OFF_BSUM   90700000UL
#define WS_NEED    91000000UL

// canonical weight offsets (elements within Wc), cumulative in input order
#define W_WL1   0
#define W_BL1   32768
#define W_WR1   33024
#define W_BR1   65792
#define W_ATT1  66048
#define W_BIAS1 66304
#define W_WL2   66560
#define W_BL2   74752
#define W_WR2   74784
#define W_BR2   82976
#define W_ATT2  83008
#define W_BIAS2 83040
#define W_TOTAL 83072

__device__ inline float b2f(u16 u) { return __uint_as_float(((unsigned)u) << 16); }
__device__ inline u16 f2b(float f) {
    unsigned u = __float_as_uint(f);
    unsigned r = (u + 0x7fffu + ((u >> 16) & 1u)) >> 16;
    return (u16)r;
}
__device__ inline unsigned cvtpk(float lo, float hi) {
    unsigned r;
    asm("v_cvt_pk_bf16_f32 %0, %1, %2" : "=v"(r) : "v"(lo), "v"(hi));
    return r;
}
__device__ inline f32x2 pk_add(f32x2 a, f32x2 b) {
    f32x2 d;
    asm("v_pk_add_f32 %0, %1, %2" : "=v"(d) : "v"(a), "v"(b));
    return d;
}
__device__ inline f32x2 pk_mul(f32x2 a, f32x2 b) {
    f32x2 d;
    asm("v_pk_mul_f32 %0, %1, %2" : "=v"(d) : "v"(a), "v"(b));
    return d;
}
__device__ inline f32x2 pk_fma(f32x2 a, f32x2 b, f32x2 c) {
    f32x2 d;
    asm("v_pk_fma_f32 %0, %1, %2, %3" : "=v"(d) : "v"(a), "v"(b), "v"(c));
    return d;
}
__device__ inline f32x2 unpk(unsigned u) {
    f32x2 d;
    d.x = __uint_as_float(u << 16);
    d.y = __uint_as_float(u & 0xffff0000u);
    return d;
}
__device__ inline f32x2 pabs(f32x2 z) {
    f32x2 d;
    d.x = __uint_as_float(__float_as_uint(z.x) & 0x7fffffffu);
    d.y = __uint_as_float(__float_as_uint(z.y) & 0x7fffffffu);
    return d;
}

// ---------------------------------------------------------------------------
// prep: weights canonicalization (blocks [0, NBW)) + degree histogram
// (blocks [NBW, ...)). (verified R8/R9)
// ---------------------------------------------------------------------------
struct WcArgs { const void* src[12]; int cum[13]; };

__global__ __launch_bounds__(256) void prep(
    WcArgs a, const u16* __restrict__ xprobe, u16* __restrict__ dst, int total,
    int* __restrict__ flagOut, int NBW,
    const int* __restrict__ ei, int* __restrict__ deg, int E_, int NP) {
    const int t = threadIdx.x;
    if ((int)blockIdx.x >= NBW) {
        int e = ((int)blockIdx.x - NBW) * 256 + t;
        if (e >= E_ + NP) return;
        int dstn = (e < E_) ? ei[E_ + e] : e - E_;
        atomicAdd(deg + dstn, 1);
        return;
    }
    __shared__ int cnt[256];
    __shared__ int sflag;
    int c = 0;
    for (int i = t; i < 512; i += 256) {
        u16 u = xprobe[i];
        int e = (u >> 7) & 0xff;
        c += (u == 0 || (e >= 100 && e <= 141)) ? 1 : 0;
    }
    cnt[t] = c; __syncthreads();
    for (int off = 128; off; off >>= 1) {
        if (t < off) cnt[t] += cnt[t + off];
        __syncthreads();
    }
    if (t == 0) {
        sflag = (cnt[0] >= 440) ? 1 : 0;
        if (blockIdx.x == 0) *flagOut = sflag;
    }
    __syncthreads();
    const int fl = sflag;
    int i = blockIdx.x * 256 + t;
    if (i >= total) return;
    int s = 0;
    while (i >= a.cum[s + 1]) s++;
    int rel = i - a.cum[s];
    if (fl) dst[i] = ((const u16*)a.src[s])[rel];
    else    dst[i] = f2b(((const float*)a.src[s])[rel]);
}

// ---------------------------------------------------------------------------
// CSR scan (2 dispatches) + degree-bucket histogram/scan folded in.
// ---------------------------------------------------------------------------
__global__ __launch_bounds__(256) void scan_part(const int* __restrict__ deg,
                                                 int* __restrict__ bsum,
                                                 int* __restrict__ dh, int NN) {
    __shared__ int red[256];
    __shared__ int lh[256];
    int b = blockIdx.x, t = threadIdx.x;
    lh[t] = 0;
    int base = b * 1024 + t * 4;
    int s = 0;
    __syncthreads();
#pragma unroll
    for (int j = 0; j < 4; j++) {
        int i = base + j;
        if (i < NN) {
            int v = deg[i];
            s += v;
            atomicAdd(&lh[v < 255 ? v : 255], 1);
        }
    }
    red[t] = s; __syncthreads();
    for (int off = 128; off; off >>= 1) {
        if (t < off) red[t] += red[t + off];
        __syncthreads();
    }
    if (t == 0) bsum[b] = red[0];
    if (lh[t]) atomicAdd(dh + t, lh[t]);
}

__global__ __launch_bounds__(256) void scan_final(
    const int* __restrict__ deg, const int* __restrict__ bsum,
    int* __restrict__ rowptr, int* __restrict__ cur, int NN, int NB,
    const int* __restrict__ dh, int* __restrict__ dcur) {
    __shared__ int sb[256];
    __shared__ int ps[256];
    int b = blockIdx.x, t = threadIdx.x;
    int bv = (t < NB) ? bsum[t] : 0;
    sb[t] = bv; __syncthreads();
    for (int off = 1; off < 256; off <<= 1) {
        int x = (t >= off) ? sb[t - off] : 0;
        __syncthreads();
        sb[t] += x;
        __syncthreads();
    }
    if (b == 0 && t == 0) rowptr[NN] = sb[NB - 1];
    int boff = (b == 0) ? 0 : sb[b - 1];

    int base = b * 1024 + t * 4;
    int v[4]; int s = 0;
#pragma unroll
    for (int j = 0; j < 4; j++) { int i = base + j; v[j] = (i < NN) ? deg[i] : 0; s += v[j]; }
    ps[t] = s; __syncthreads();
    for (int off = 1; off < 256; off <<= 1) {
        int x = (t >= off) ? ps[t - off] : 0;
        __syncthreads();
        ps[t] += x;
        __syncthreads();
    }
    int run = boff + (t ? ps[t - 1] : 0);
#pragma unroll
    for (int j = 0; j < 4; j++) {
        int i = base + j;
        if (i < NN) { rowptr[i] = run; cur[i] = run; run += v[j]; }
    }

    // block 0: exclusive scan of the 256 degree buckets -> dcur
    if (b == 0) {
        __syncthreads();
        int dv = dh[t];
        sb[t] = dv; __syncthreads();
        for (int off = 1; off < 256; off <<= 1) {
            int x = (t >= off) ? sb[t - off] : 0;
            __syncthreads();
            sb[t] += x;
            __syncthreads();
        }
        dcur[t] = sb[t] - dv;
    }
}

// counting-sort scatter: perm = nodes ordered by degree bucket
__global__ void dsort_scatter(const int* __restrict__ deg, int* __restrict__ dcur,
                              int* __restrict__ perm, int NN) {
    int i = blockIdx.x * 256 + threadIdx.x;
    if (i >= NN) return;
    int v = deg[i];
    int pos = atomicAdd(dcur + (v < 255 ? v : 255), 1);
    perm[pos] = i;
}

// ---------------------------------------------------------------------------
// GEMM body (verified R9): Y[m][2*JH] = X[m][K] @ [Wl;Wr]^T + [bl;br].
// ---------------------------------------------------------------------------
template <int K, int NG, bool DYN>
__device__ __forceinline__ void gemm_body(
    float (*cs)[32][68],
    const void* __restrict__ X, const u16* __restrict__ Wl, const u16* __restrict__ Wr,
    const u16* __restrict__ bl, const u16* __restrict__ br,
    u16* __restrict__ Y, int M, int JH, const int* __restrict__ flagp, int bm0) {
    const int t = threadIdx.x, w = t >> 6, l = t & 63;
    const int JT = 2 * JH;
    const int lr = l & 15, lk = (l >> 4) * 8;
    const int fl = DYN ? *flagp : 1;

    int rowm[2];
#pragma unroll
    for (int mt = 0; mt < 2; mt++) {
        int row = bm0 + w * 32 + mt * 16 + lr;
        if (row >= M) row = M - 1;
        rowm[mt] = row;
    }

    constexpr int KK = K / 32;
    bf16x8 afr[2][KK];
    if (fl) {
        const u16* xb = (const u16*)X;
#pragma unroll
        for (int mt = 0; mt < 2; mt++)
#pragma unroll
            for (int kk = 0; kk < KK; kk++)
                afr[mt][kk] = *(const bf16x8*)(xb + (size_t)rowm[mt] * K + lk + kk * 32);
    } else {
        const float* xf = (const float*)X;
#pragma unroll
        for (int mt = 0; mt < 2; mt++)
#pragma unroll
            for (int kk = 0; kk < KK; kk++) {
                const float* p = xf + (size_t)rowm[mt] * K + lk + kk * 32;
                float4 v0 = *(const float4*)p;
                float4 v1 = *(const float4*)(p + 4);
                uint4 o;
                o.x = cvtpk(v0.x, v0.y); o.y = cvtpk(v0.z, v0.w);
                o.z = cvtpk(v1.x, v1.y); o.w = cvtpk(v1.z, v1.w);
                afr[mt][kk] = *(bf16x8*)&o;
            }
    }

#pragma unroll 1
    for (int g = 0; g < NG; g++) {
        const int bn0 = g * 64;
        const u16* bx[4];
        float bv[4];
#pragma unroll
        for (int nt = 0; nt < 4; nt++) {
            int j = bn0 + nt * 16 + lr;
            const u16* wp = (j < JH) ? (Wl + (size_t)j * K) : (Wr + (size_t)(j - JH) * K);
            bx[nt] = wp + lk;
            bv[nt] = b2f(j < JH ? bl[j] : br[j - JH]);
        }

        f32x4 acc[2][4];
#pragma unroll
        for (int mt = 0; mt < 2; mt++)
#pragma unroll
            for (int nt = 0; nt < 4; nt++) acc[mt][nt] = (f32x4){0.f, 0.f, 0.f, 0.f};

#pragma unroll
        for (int kk = 0; kk < KK; kk++) {
            bf16x8 b[4];
#pragma unroll
            for (int nt = 0; nt < 4; nt++) b[nt] = *(const bf16x8*)(bx[nt] + kk * 32);
#pragma unroll
            for (int mt = 0; mt < 2; mt++)
#pragma unroll
                for (int nt = 0; nt < 4; nt++)
                    acc[mt][nt] = __builtin_amdgcn_mfma_f32_16x16x32_bf16(
                        afr[mt][kk], b[nt], acc[mt][nt], 0, 0, 0);
        }

#pragma unroll
        for (int mt = 0; mt < 2; mt++)
#pragma unroll
            for (int nt = 0; nt < 4; nt++)
#pragma unroll
                for (int r = 0; r < 4; r++)
                    cs[w][mt * 16 + (l >> 4) * 4 + r][nt * 16 + lr] = acc[mt][nt][r] + bv[nt];

#pragma unroll
        for (int p = 0; p < 4; p++) {
            int rl = p * 8 + (l >> 3);
            int grow = bm0 + w * 32 + rl;
            if (grow < M) {
                const float* rp = &cs[w][rl][(l & 7) * 8];
                float4 v0 = *(const float4*)rp;
                float4 v1 = *(const float4*)(rp + 4);
                uint4 o;
                o.x = cvtpk(v0.x, v0.y); o.y = cvtpk(v0.z, v0.w);
                o.z = cvtpk(v1.x, v1.y); o.w = cvtpk(v1.z, v1.w);
                *(uint4*)(Y + (size_t)grow * JT + bn0 + (l & 7) * 8) = o;
            }
        }
    }
}

// fused: blocks [0,NBG) = layer-1 GEMM; blocks [NBG,..) = edge scatter.
__global__ __launch_bounds__(256) void gemm1_scatter(
    const void* __restrict__ X, const u16* __restrict__ Wl, const u16* __restrict__ Wr,
    const u16* __restrict__ bl, const u16* __restrict__ br,
    u16* __restrict__ Y, int M, const int* __restrict__ flagp, int NBG,
    const int* __restrict__ ei, int* __restrict__ cur, int* __restrict__ col,
    int E_, int NP) {
    __shared__ float cs[4][32][68];
    if ((int)blockIdx.x < NBG) {
        gemm_body<F_IN, 8, true>(cs, X, Wl, Wr, bl, br, Y, M, JH1, flagp,
                                 (int)blockIdx.x * 128);
        return;
    }
    int e = ((int)blockIdx.x - NBG) * 256 + threadIdx.x;
    if (e >= E_ + NP) return;
    int src, dst;
    if (e < E_) { src = ei[e]; dst = ei[E_ + e]; }
    else        { src = dst = e - E_; }
    int pos = atomicAdd(cur + dst, 1);
    col[pos] = src;
}

__global__ __launch_bounds__(256) void gemm2_k(
    const u16* __restrict__ X, const u16* __restrict__ Wl, const u16* __restrict__ Wr,
    const u16* __restrict__ bl, const u16* __restrict__ br,
    u16* __restrict__ Y, int M, const int* __restrict__ flagp) {
    __shared__ float cs[4][32][68];
    gemm_body<JH1, 1, false>(cs, X, Wl, Wr, bl, br, Y, M, JH2, flagp,
                             (int)blockIdx.x * 128);
}

// ---------------------------------------------------------------------------
// Layer-1 aggregate (R13 structure, proven 92us) with degree-sorted node
// assignment: n = perm[wid], so the 4 waves of a block get equal-degree
// nodes (no straggler wave-slots).
// ---------------------------------------------------------------------------
__global__ __launch_bounds__(256, 4) void agg1(
    const u16* __restrict__ Y1, const int* __restrict__ rowptr,
    const int* __restrict__ col, const u16* __restrict__ att,
    const u16* __restrict__ bias, u16* __restrict__ hout, int NN,
    const int* __restrict__ perm) {
    const int wid = blockIdx.x * 4 + (threadIdx.x >> 6);
    if (wid >= NN) return;
    const int lane = threadIdx.x & 63, half = lane >> 5, hl = lane & 31;
    const int n = perm[wid];

    f32x2 xr2[4], a06[4], a04[4];
    {
        uint4 rx = *(const uint4*)(Y1 + (size_t)n * JT1 + JH1 + hl * 8);
        uint4 ra = *(const uint4*)(att + hl * 8);
        unsigned ux[4] = {rx.x, rx.y, rx.z, rx.w};
        unsigned ua[4] = {ra.x, ra.y, ra.z, ra.w};
#pragma unroll
        for (int p = 0; p < 4; p++) {
            xr2[p] = unpk(ux[p]);
            f32x2 a = unpk(ua[p]);
            a06[p].x = 0.6f * a.x; a06[p].y = 0.6f * a.y;
            a04[p].x = 0.4f * a.x; a04[p].y = 0.4f * a.y;
        }
    }
    f32x2 acc2[4] = {{0.f,0.f},{0.f,0.f},{0.f,0.f},{0.f,0.f}};
    float dsum = 0.f;

    auto edge = [&](uint4 raw) {
        unsigned uw[4] = {raw.x, raw.y, raw.z, raw.w};
        f32x2 xl2[4];
        f32x2 p2 = {0.f, 0.f};
#pragma unroll
        for (int p = 0; p < 4; p++) {
            xl2[p] = unpk(uw[p]);
            f32x2 z = pk_add(xl2[p], xr2[p]);
            p2 = pk_fma(z, a06[p], p2);
            p2 = pk_fma(pabs(z), a04[p], p2);
        }
        float pl = p2.x + p2.y;
        pl += __shfl_xor(pl, 1); pl += __shfl_xor(pl, 2);
        float e = __expf(pl);
        dsum += e;
        f32x2 e2; e2.x = e; e2.y = e;
#pragma unroll
        for (int p = 0; p < 4; p++) acc2[p] = pk_fma(e2, xl2[p], acc2[p]);
    };

    const int beg = rowptr[n], end = rowptr[n + 1];
    int i = beg + half;
    for (; i + 14 < end; i += 16) {
        int s[8];
#pragma unroll
        for (int k = 0; k < 8; k++) s[k] = col[i + 2 * k];
        uint4 r[8];
#pragma unroll
        for (int k = 0; k < 8; k++) r[k] = *(const uint4*)(Y1 + (size_t)s[k] * JT1 + hl * 8);
#pragma unroll
        for (int k = 0; k < 8; k++) edge(r[k]);
    }
    for (; i + 6 < end; i += 8) {
        int s0 = col[i], s1 = col[i + 2], s2 = col[i + 4], s3 = col[i + 6];
        uint4 r0 = *(const uint4*)(Y1 + (size_t)s0 * JT1 + hl * 8);
        uint4 r1 = *(const uint4*)(Y1 + (size_t)s1 * JT1 + hl * 8);
        uint4 r2 = *(const uint4*)(Y1 + (size_t)s2 * JT1 + hl * 8);
        uint4 r3 = *(const uint4*)(Y1 + (size_t)s3 * JT1 + hl * 8);
        edge(r0); edge(r1); edge(r2); edge(r3);
    }
    for (; i < end; i += 2) {
        uint4 r0 = *(const uint4*)(Y1 + (size_t)col[i] * JT1 + hl * 8);
        edge(r0);
    }

    dsum += __shfl_xor(dsum, 32);
#pragma unroll
    for (int p = 0; p < 4; p++) {
        acc2[p].x += __shfl_xor(acc2[p].x, 32);
        acc2[p].y += __shfl_xor(acc2[p].y, 32);
    }

    if (half == 0) {
        float inv = 1.f / fmaxf(dsum, 1e-16f);
        u16 bu[8];
        *(uint4*)bu = *(const uint4*)(bias + hl * 8);
        float v[8];
#pragma unroll
        for (int p = 0; p < 4; p++) {
            float x0 = acc2[p].x * inv + b2f(bu[2 * p]);
            float x1 = acc2[p].y * inv + b2f(bu[2 * p + 1]);
            v[2 * p]     = 0.5f * x0 * (1.f + erff(x0 * 0.70710678118654752f));
            v[2 * p + 1] = 0.5f * x1 * (1.f + erff(x1 * 0.70710678118654752f));
        }
        uint4 o;
        o.x = cvtpk(v[0], v[1]); o.y = cvtpk(v[2], v[3]);
        o.z = cvtpk(v[4], v[5]); o.w = cvtpk(v[6], v[7]);
        *(uint4*)(hout + (size_t)n * JH1 + hl * 8) = o;
    }
}

// ---------------------------------------------------------------------------
// Layer-2 aggregate (R13 structure) with degree-sorted node assignment.
// ---------------------------------------------------------------------------
__global__ __launch_bounds__(256) void agg2(
    const u16* __restrict__ Y2, const int* __restrict__ rowptr,
    const int* __restrict__ col, const u16* __restrict__ att,
    const u16* __restrict__ bias, void* __restrict__ dout, int NN,
    const int* __restrict__ flag, const int* __restrict__ perm) {
    const int wid = blockIdx.x * 4 + (threadIdx.x >> 6);
    if (wid >= NN) return;
    const int lane = threadIdx.x & 63, le = lane >> 4, cl = lane & 15;
    const int n = perm[wid];

    f32x2 xr2 = unpk(*(const unsigned*)(Y2 + (size_t)n * JT2 + JH2 + cl * 2));
    f32x2 av  = unpk(*(const unsigned*)(att + cl * 2));
    f32x2 a06; a06.x = 0.6f * av.x; a06.y = 0.6f * av.y;
    f32x2 a04; a04.x = 0.4f * av.x; a04.y = 0.4f * av.y;
    f32x2 acc2 = {0.f, 0.f};
    float dsum = 0.f;

    auto edge = [&](unsigned raw, bool act) {
        f32x2 xl2 = unpk(raw);
        f32x2 z = pk_add(xl2, xr2);
        f32x2 p2 = pk_fma(z, a06, (f32x2){0.f, 0.f});
        p2 = pk_fma(pabs(z), a04, p2);
        float pl = p2.x + p2.y;
        pl += __shfl_xor(pl, 1); pl += __shfl_xor(pl, 2);
        pl += __shfl_xor(pl, 4); pl += __shfl_xor(pl, 8);
        float e = __expf(pl);
        if (!act) e = 0.f;
        dsum += e;
        f32x2 e2; e2.x = e; e2.y = e;
        acc2 = pk_fma(e2, xl2, acc2);
    };

    const int beg = rowptr[n], end = rowptr[n + 1];
    int i = beg;
    for (; i + 16 <= end; i += 16) {
        int s0 = col[i + le], s1 = col[i + 4 + le];
        int s2 = col[i + 8 + le], s3 = col[i + 12 + le];
        unsigned r0 = *(const unsigned*)(Y2 + (size_t)s0 * JT2 + cl * 2);
        unsigned r1 = *(const unsigned*)(Y2 + (size_t)s1 * JT2 + cl * 2);
        unsigned r2 = *(const unsigned*)(Y2 + (size_t)s2 * JT2 + cl * 2);
        unsigned r3 = *(const unsigned*)(Y2 + (size_t)s3 * JT2 + cl * 2);
        edge(r0, true); edge(r1, true); edge(r2, true); edge(r3, true);
    }
    for (; i + 8 <= end; i += 8) {
        int sA = col[i + le];
        int sB = col[i + 4 + le];
        unsigned rA = *(const unsigned*)(Y2 + (size_t)sA * JT2 + cl * 2);
        unsigned rB = *(const unsigned*)(Y2 + (size_t)sB * JT2 + cl * 2);
        edge(rA, true);
        edge(rB, true);
    }
    for (; i < end; i += 4) {
        int idx = i + le;
        bool act = idx < end;
        int s0 = col[act ? idx : end - 1];
        unsigned r0 = *(const unsigned*)(Y2 + (size_t)s0 * JT2 + cl * 2);
        edge(r0, act);
    }

    dsum += __shfl_xor(dsum, 16); dsum += __shfl_xor(dsum, 32);
    acc2.x += __shfl_xor(acc2.x, 16); acc2.x += __shfl_xor(acc2.x, 32);
    acc2.y += __shfl_xor(acc2.y, 16); acc2.y += __shfl_xor(acc2.y, 32);

    if (le == 0) {
        float inv = 1.f / fmaxf(dsum, 1e-16f);
        f32x2 bv = unpk(*(const unsigned*)(bias + cl * 2));
        float v0 = acc2.x * inv + bv.x;
        float v1 = acc2.y * inv + bv.y;
        if (*flag) {
            *(unsigned*)((u16*)dout + n * JH2 + cl * 2) = cvtpk(v0, v1);
        } else {
            float2 o; o.x = v0; o.y = v1;
            *(float2*)((float*)dout + n * JH2 + cl * 2) = o;
        }
    }
}

extern "C" void kernel_launch(void* const* d_in, const int* in_sizes, int n_in,
                              void* d_out, int out_size, void* d_ws, size_t ws_size,
                              hipStream_t stream) {
    const int NN = in_sizes[0] / F_IN;   // 50000
    const int EE = in_sizes[1] / 2;      // 800000
    const int EP = EE + NN;
    if (ws_size < WS_NEED) return;

    char* w = (char*)d_ws;
    u16*   Y1   = (u16*)(w + OFF_Y1);
    u16*   hbuf = (u16*)(w + OFF_H);
    u16*   Y2   = (u16*)(w + OFF_Y2);
    int*   col  = (int*)(w + OFF_COL);
    int*   perm = (int*)(w + OFF_PERM);
    int*   deg  = (int*)(w + OFF_DEG);
    int*   dh   = (int*)(w + OFF_DH);
    int*   dcur = (int*)(w + OFF_DCUR);
    int*   rowp = (int*)(w + OFF_ROW);
    int*   cur  = (int*)(w + OFF_CUR);
    u16*   Wc   = (u16*)(w + OFF_WC);
    int*   flag = (int*)(w + OFF_FLAG);
    int*   bsum = (int*)(w + OFF_BSUM);

    const int* ei = (const int*)d_in[1];

    // 1) zero deg + bucket hist/cursors (contiguous), then fused prep
    hipMemsetAsync(deg, 0, (size_t)NN * 4 + 2048, stream);
    {
        WcArgs a;
        int sizes[12] = {JH1 * F_IN, JH1, JH1 * F_IN, JH1, H1 * CH, JH1,
                         JH2 * JH1, JH2, JH2 * JH1, JH2, JH2, JH2};
        int c = 0;
        for (int s = 0; s < 12; s++) { a.src[s] = d_in[2 + s]; a.cum[s] = c; c += sizes[s]; }
        a.cum[12] = c;
        const int NBW = (W_TOTAL + 255) / 256;
        const int NBE = (EP + 255) / 256;
        prep<<<NBW + NBE, 256, 0, stream>>>(a, (const u16*)d_in[0], Wc, W_TOTAL,
                                            flag, NBW, ei, deg, EE, NN);
    }

    // 2) CSR scan (+ degree-bucket hist/scan) + degree-sort scatter
    const int NB = (NN + 1023) / 1024;   // 49 (<=256 supported)
    scan_part<<<NB, 256, 0, stream>>>(deg, bsum, dh, NN);
    scan_final<<<NB, 256, 0, stream>>>(deg, bsum, rowp, cur, NN, NB, dh, dcur);
    dsort_scatter<<<(NN + 255) / 256, 256, 0, stream>>>(deg, dcur, perm, NN);

    // 3) layer-1 GEMM fused with edge scatter
    {
        const int NBG = (NN + 127) / 128;
        const int NBE = (EP + 255) / 256;
        gemm1_scatter<<<NBG + NBE, 256, 0, stream>>>(
            d_in[0], Wc + W_WL1, Wc + W_WR1, Wc + W_BL1, Wc + W_BR1,
            Y1, NN, flag, NBG, ei, cur, col, EE, NN);
    }
    agg1<<<(NN + 3) / 4, 256, 0, stream>>>(Y1, rowp, col, Wc + W_ATT1,
                                           Wc + W_BIAS1, hbuf, NN, perm);

    // 4) layer 2
    gemm2_k<<<(NN + 127) / 128, 256, 0, stream>>>(
        hbuf, Wc + W_WL2, Wc + W_WR2, Wc + W_BL2, Wc + W_BR2, Y2, NN, flag);
    agg2<<<(NN + 3) / 4, 256, 0, stream>>>(Y2, rowp, col, Wc + W_ATT2,
                                           Wc + W_BIAS2, d_out, NN, flag, perm);
}

// Round 17
// 240.875 us; speedup vs baseline: 1.5889x; 1.5889x over previous
//
#include <hip/hip_runtime.h>
#include <hip/hip_bf16.h>

// ---------------------------------------------------------------------------
// GATv2 x2 (PyG GATv2Conv semantics with self-loops), MI355X.
// R17: exact restore of R13 (best known, 243.2us, validated twice).
// R16's degree-sort was a null for agg1 and its scatter cost 139us
// (50k atomics over 256 cursors). All agg1 levers now tested and closed:
// pipeline depth (8 = opt), edge-width (2/wave = opt), layout (interleaved =
// opt), NT hints (null), load balance (null). agg1 = structural gather floor.
// ---------------------------------------------------------------------------

typedef unsigned short u16;
typedef short bf16x8 __attribute__((ext_vector_type(8)));
typedef float f32x4 __attribute__((ext_vector_type(4)));
typedef float f32x2 __attribute__((ext_vector_type(2)));

#define F_IN   128
#define CH     32
#define H1     8
#define JT1    512   // 2 * H1*CH  (xl | xr concatenated)
#define JH1    256   // H1*CH
#define JT2    64    // 2 * CH
#define JH2    32

// ---- ws layout (bytes) ----------------------------------------------------
#define OFF_Y1     0UL
#define OFF_H      52000000UL
#define OFF_Y2     78000000UL
#define OFF_COL    85000000UL
#define OFF_DEG    89000000UL
#define OFF_ROW    89400000UL
#define OFF_CUR    89800000UL
#define OFF_WC     90200000UL
#define OFF_FLAG   90600000UL
#define OFF_BSUM   90700000UL
#define WS_NEED    91000000UL

// canonical weight offsets (elements within Wc), cumulative in input order
#define W_WL1   0
#define W_BL1   32768
#define W_WR1   33024
#define W_BR1   65792
#define W_ATT1  66048
#define W_BIAS1 66304
#define W_WL2   66560
#define W_BL2   74752
#define W_WR2   74784
#define W_BR2   82976
#define W_ATT2  83008
#define W_BIAS2 83040
#define W_TOTAL 83072

__device__ inline float b2f(u16 u) { return __uint_as_float(((unsigned)u) << 16); }
__device__ inline u16 f2b(float f) {
    unsigned u = __float_as_uint(f);
    unsigned r = (u + 0x7fffu + ((u >> 16) & 1u)) >> 16;
    return (u16)r;
}
__device__ inline unsigned cvtpk(float lo, float hi) {
    unsigned r;
    asm("v_cvt_pk_bf16_f32 %0, %1, %2" : "=v"(r) : "v"(lo), "v"(hi));
    return r;
}
__device__ inline f32x2 pk_add(f32x2 a, f32x2 b) {
    f32x2 d;
    asm("v_pk_add_f32 %0, %1, %2" : "=v"(d) : "v"(a), "v"(b));
    return d;
}
__device__ inline f32x2 pk_mul(f32x2 a, f32x2 b) {
    f32x2 d;
    asm("v_pk_mul_f32 %0, %1, %2" : "=v"(d) : "v"(a), "v"(b));
    return d;
}
__device__ inline f32x2 pk_fma(f32x2 a, f32x2 b, f32x2 c) {
    f32x2 d;
    asm("v_pk_fma_f32 %0, %1, %2, %3" : "=v"(d) : "v"(a), "v"(b), "v"(c));
    return d;
}
__device__ inline f32x2 unpk(unsigned u) {
    f32x2 d;
    d.x = __uint_as_float(u << 16);
    d.y = __uint_as_float(u & 0xffff0000u);
    return d;
}
__device__ inline f32x2 pabs(f32x2 z) {
    f32x2 d;
    d.x = __uint_as_float(__float_as_uint(z.x) & 0x7fffffffu);
    d.y = __uint_as_float(__float_as_uint(z.y) & 0x7fffffffu);
    return d;
}

// ---------------------------------------------------------------------------
// prep: weights canonicalization (blocks [0, NBW)) + degree histogram
// (blocks [NBW, ...)). (verified R8/R9/R13)
// ---------------------------------------------------------------------------
struct WcArgs { const void* src[12]; int cum[13]; };

__global__ __launch_bounds__(256) void prep(
    WcArgs a, const u16* __restrict__ xprobe, u16* __restrict__ dst, int total,
    int* __restrict__ flagOut, int NBW,
    const int* __restrict__ ei, int* __restrict__ deg, int E_, int NP) {
    const int t = threadIdx.x;
    if ((int)blockIdx.x >= NBW) {
        int e = ((int)blockIdx.x - NBW) * 256 + t;
        if (e >= E_ + NP) return;
        int dstn = (e < E_) ? ei[E_ + e] : e - E_;
        atomicAdd(deg + dstn, 1);
        return;
    }
    __shared__ int cnt[256];
    __shared__ int sflag;
    int c = 0;
    for (int i = t; i < 512; i += 256) {
        u16 u = xprobe[i];
        int e = (u >> 7) & 0xff;
        c += (u == 0 || (e >= 100 && e <= 141)) ? 1 : 0;
    }
    cnt[t] = c; __syncthreads();
    for (int off = 128; off; off >>= 1) {
        if (t < off) cnt[t] += cnt[t + off];
        __syncthreads();
    }
    if (t == 0) {
        sflag = (cnt[0] >= 440) ? 1 : 0;
        if (blockIdx.x == 0) *flagOut = sflag;
    }
    __syncthreads();
    const int fl = sflag;
    int i = blockIdx.x * 256 + t;
    if (i >= total) return;
    int s = 0;
    while (i >= a.cum[s + 1]) s++;
    int rel = i - a.cum[s];
    if (fl) dst[i] = ((const u16*)a.src[s])[rel];
    else    dst[i] = f2b(((const float*)a.src[s])[rel]);
}

// ---------------------------------------------------------------------------
// CSR scan (2 dispatches), verified R7-R9/R13
// ---------------------------------------------------------------------------
__global__ __launch_bounds__(256) void scan_part(const int* __restrict__ deg,
                                                 int* __restrict__ bsum, int NN) {
    __shared__ int red[256];
    int b = blockIdx.x, t = threadIdx.x;
    int base = b * 1024 + t * 4;
    int s = 0;
#pragma unroll
    for (int j = 0; j < 4; j++) { int i = base + j; if (i < NN) s += deg[i]; }
    red[t] = s; __syncthreads();
    for (int off = 128; off; off >>= 1) {
        if (t < off) red[t] += red[t + off];
        __syncthreads();
    }
    if (t == 0) bsum[b] = red[0];
}

__global__ __launch_bounds__(256) void scan_final(
    const int* __restrict__ deg, const int* __restrict__ bsum,
    int* __restrict__ rowptr, int* __restrict__ cur, int NN, int NB) {
    __shared__ int sb[256];
    __shared__ int ps[256];
    int b = blockIdx.x, t = threadIdx.x;
    int bv = (t < NB) ? bsum[t] : 0;
    sb[t] = bv; __syncthreads();
    for (int off = 1; off < 256; off <<= 1) {
        int x = (t >= off) ? sb[t - off] : 0;
        __syncthreads();
        sb[t] += x;
        __syncthreads();
    }
    if (b == 0 && t == 0) rowptr[NN] = sb[NB - 1];
    int boff = (b == 0) ? 0 : sb[b - 1];

    int base = b * 1024 + t * 4;
    int v[4]; int s = 0;
#pragma unroll
    for (int j = 0; j < 4; j++) { int i = base + j; v[j] = (i < NN) ? deg[i] : 0; s += v[j]; }
    ps[t] = s; __syncthreads();
    for (int off = 1; off < 256; off <<= 1) {
        int x = (t >= off) ? ps[t - off] : 0;
        __syncthreads();
        ps[t] += x;
        __syncthreads();
    }
    int run = boff + (t ? ps[t - 1] : 0);
#pragma unroll
    for (int j = 0; j < 4; j++) {
        int i = base + j;
        if (i < NN) { rowptr[i] = run; cur[i] = run; run += v[j]; }
    }
}

// ---------------------------------------------------------------------------
// GEMM body (verified R9/R13): Y[m][2*JH] = X[m][K] @ [Wl;Wr]^T + [bl;br].
// A fragments loaded once; loop over NG 64-column groups. Interleaved Y.
// ---------------------------------------------------------------------------
template <int K, int NG, bool DYN>
__device__ __forceinline__ void gemm_body(
    float (*cs)[32][68],
    const void* __restrict__ X, const u16* __restrict__ Wl, const u16* __restrict__ Wr,
    const u16* __restrict__ bl, const u16* __restrict__ br,
    u16* __restrict__ Y, int M, int JH, const int* __restrict__ flagp, int bm0) {
    const int t = threadIdx.x, w = t >> 6, l = t & 63;
    const int JT = 2 * JH;
    const int lr = l & 15, lk = (l >> 4) * 8;
    const int fl = DYN ? *flagp : 1;

    int rowm[2];
#pragma unroll
    for (int mt = 0; mt < 2; mt++) {
        int row = bm0 + w * 32 + mt * 16 + lr;
        if (row >= M) row = M - 1;
        rowm[mt] = row;
    }

    constexpr int KK = K / 32;
    bf16x8 afr[2][KK];
    if (fl) {
        const u16* xb = (const u16*)X;
#pragma unroll
        for (int mt = 0; mt < 2; mt++)
#pragma unroll
            for (int kk = 0; kk < KK; kk++)
                afr[mt][kk] = *(const bf16x8*)(xb + (size_t)rowm[mt] * K + lk + kk * 32);
    } else {
        const float* xf = (const float*)X;
#pragma unroll
        for (int mt = 0; mt < 2; mt++)
#pragma unroll
            for (int kk = 0; kk < KK; kk++) {
                const float* p = xf + (size_t)rowm[mt] * K + lk + kk * 32;
                float4 v0 = *(const float4*)p;
                float4 v1 = *(const float4*)(p + 4);
                uint4 o;
                o.x = cvtpk(v0.x, v0.y); o.y = cvtpk(v0.z, v0.w);
                o.z = cvtpk(v1.x, v1.y); o.w = cvtpk(v1.z, v1.w);
                afr[mt][kk] = *(bf16x8*)&o;
            }
    }

#pragma unroll 1
    for (int g = 0; g < NG; g++) {
        const int bn0 = g * 64;
        const u16* bx[4];
        float bv[4];
#pragma unroll
        for (int nt = 0; nt < 4; nt++) {
            int j = bn0 + nt * 16 + lr;
            const u16* wp = (j < JH) ? (Wl + (size_t)j * K) : (Wr + (size_t)(j - JH) * K);
            bx[nt] = wp + lk;
            bv[nt] = b2f(j < JH ? bl[j] : br[j - JH]);
        }

        f32x4 acc[2][4];
#pragma unroll
        for (int mt = 0; mt < 2; mt++)
#pragma unroll
            for (int nt = 0; nt < 4; nt++) acc[mt][nt] = (f32x4){0.f, 0.f, 0.f, 0.f};

#pragma unroll
        for (int kk = 0; kk < KK; kk++) {
            bf16x8 b[4];
#pragma unroll
            for (int nt = 0; nt < 4; nt++) b[nt] = *(const bf16x8*)(bx[nt] + kk * 32);
#pragma unroll
            for (int mt = 0; mt < 2; mt++)
#pragma unroll
                for (int nt = 0; nt < 4; nt++)
                    acc[mt][nt] = __builtin_amdgcn_mfma_f32_16x16x32_bf16(
                        afr[mt][kk], b[nt], acc[mt][nt], 0, 0, 0);
        }

#pragma unroll
        for (int mt = 0; mt < 2; mt++)
#pragma unroll
            for (int nt = 0; nt < 4; nt++)
#pragma unroll
                for (int r = 0; r < 4; r++)
                    cs[w][mt * 16 + (l >> 4) * 4 + r][nt * 16 + lr] = acc[mt][nt][r] + bv[nt];

#pragma unroll
        for (int p = 0; p < 4; p++) {
            int rl = p * 8 + (l >> 3);
            int grow = bm0 + w * 32 + rl;
            if (grow < M) {
                const float* rp = &cs[w][rl][(l & 7) * 8];
                float4 v0 = *(const float4*)rp;
                float4 v1 = *(const float4*)(rp + 4);
                uint4 o;
                o.x = cvtpk(v0.x, v0.y); o.y = cvtpk(v0.z, v0.w);
                o.z = cvtpk(v1.x, v1.y); o.w = cvtpk(v1.z, v1.w);
                *(uint4*)(Y + (size_t)grow * JT + bn0 + (l & 7) * 8) = o;
            }
        }
    }
}

// fused: blocks [0,NBG) = layer-1 GEMM; blocks [NBG,..) = edge scatter.
__global__ __launch_bounds__(256) void gemm1_scatter(
    const void* __restrict__ X, const u16* __restrict__ Wl, const u16* __restrict__ Wr,
    const u16* __restrict__ bl, const u16* __restrict__ br,
    u16* __restrict__ Y, int M, const int* __restrict__ flagp, int NBG,
    const int* __restrict__ ei, int* __restrict__ cur, int* __restrict__ col,
    int E_, int NP) {
    __shared__ float cs[4][32][68];
    if ((int)blockIdx.x < NBG) {
        gemm_body<F_IN, 8, true>(cs, X, Wl, Wr, bl, br, Y, M, JH1, flagp,
                                 (int)blockIdx.x * 128);
        return;
    }
    int e = ((int)blockIdx.x - NBG) * 256 + threadIdx.x;
    if (e >= E_ + NP) return;
    int src, dst;
    if (e < E_) { src = ei[e]; dst = ei[E_ + e]; }
    else        { src = dst = e - E_; }
    int pos = atomicAdd(cur + dst, 1);
    col[pos] = src;
}

__global__ __launch_bounds__(256) void gemm2_k(
    const u16* __restrict__ X, const u16* __restrict__ Wl, const u16* __restrict__ Wr,
    const u16* __restrict__ bl, const u16* __restrict__ br,
    u16* __restrict__ Y, int M, const int* __restrict__ flagp) {
    __shared__ float cs[4][32][68];
    gemm_body<JH1, 1, false>(cs, X, Wl, Wr, bl, br, Y, M, JH2, flagp,
                             (int)blockIdx.x * 128);
}

// ---------------------------------------------------------------------------
// Layer-1 aggregate (proven 92us): one wave per dst node, 2 edges/wave
// (one per 32-lane half), 8 ch/lane, packed-fp32 abs-form leaky, 8-deep
// gather pipeline (16 rows in flight). Per-head softmax via 4-lane reduce.
// Fused /denom + bias + GELU.
// ---------------------------------------------------------------------------
__global__ __launch_bounds__(256, 4) void agg1(
    const u16* __restrict__ Y1, const int* __restrict__ rowptr,
    const int* __restrict__ col, const u16* __restrict__ att,
    const u16* __restrict__ bias, u16* __restrict__ hout, int NN) {
    const int wid = blockIdx.x * 4 + (threadIdx.x >> 6);
    if (wid >= NN) return;
    const int lane = threadIdx.x & 63, half = lane >> 5, hl = lane & 31;
    const int n = wid;

    f32x2 xr2[4], a06[4], a04[4];
    {
        uint4 rx = *(const uint4*)(Y1 + (size_t)n * JT1 + JH1 + hl * 8);
        uint4 ra = *(const uint4*)(att + hl * 8);
        unsigned ux[4] = {rx.x, rx.y, rx.z, rx.w};
        unsigned ua[4] = {ra.x, ra.y, ra.z, ra.w};
#pragma unroll
        for (int p = 0; p < 4; p++) {
            xr2[p] = unpk(ux[p]);
            f32x2 a = unpk(ua[p]);
            a06[p].x = 0.6f * a.x; a06[p].y = 0.6f * a.y;
            a04[p].x = 0.4f * a.x; a04[p].y = 0.4f * a.y;
        }
    }
    f32x2 acc2[4] = {{0.f,0.f},{0.f,0.f},{0.f,0.f},{0.f,0.f}};
    float dsum = 0.f;

    auto edge = [&](uint4 raw) {
        unsigned uw[4] = {raw.x, raw.y, raw.z, raw.w};
        f32x2 xl2[4];
        f32x2 p2 = {0.f, 0.f};
#pragma unroll
        for (int p = 0; p < 4; p++) {
            xl2[p] = unpk(uw[p]);
            f32x2 z = pk_add(xl2[p], xr2[p]);
            p2 = pk_fma(z, a06[p], p2);
            p2 = pk_fma(pabs(z), a04[p], p2);
        }
        float pl = p2.x + p2.y;
        pl += __shfl_xor(pl, 1); pl += __shfl_xor(pl, 2);
        float e = __expf(pl);
        dsum += e;
        f32x2 e2; e2.x = e; e2.y = e;
#pragma unroll
        for (int p = 0; p < 4; p++) acc2[p] = pk_fma(e2, xl2[p], acc2[p]);
    };

    const int beg = rowptr[n], end = rowptr[n + 1];
    int i = beg + half;
    for (; i + 14 < end; i += 16) {
        int s[8];
#pragma unroll
        for (int k = 0; k < 8; k++) s[k] = col[i + 2 * k];
        uint4 r[8];
#pragma unroll
        for (int k = 0; k < 8; k++) r[k] = *(const uint4*)(Y1 + (size_t)s[k] * JT1 + hl * 8);
#pragma unroll
        for (int k = 0; k < 8; k++) edge(r[k]);
    }
    for (; i + 6 < end; i += 8) {
        int s0 = col[i], s1 = col[i + 2], s2 = col[i + 4], s3 = col[i + 6];
        uint4 r0 = *(const uint4*)(Y1 + (size_t)s0 * JT1 + hl * 8);
        uint4 r1 = *(const uint4*)(Y1 + (size_t)s1 * JT1 + hl * 8);
        uint4 r2 = *(const uint4*)(Y1 + (size_t)s2 * JT1 + hl * 8);
        uint4 r3 = *(const uint4*)(Y1 + (size_t)s3 * JT1 + hl * 8);
        edge(r0); edge(r1); edge(r2); edge(r3);
    }
    for (; i < end; i += 2) {
        uint4 r0 = *(const uint4*)(Y1 + (size_t)col[i] * JT1 + hl * 8);
        edge(r0);
    }

    dsum += __shfl_xor(dsum, 32);
#pragma unroll
    for (int p = 0; p < 4; p++) {
        acc2[p].x += __shfl_xor(acc2[p].x, 32);
        acc2[p].y += __shfl_xor(acc2[p].y, 32);
    }

    if (half == 0) {
        float inv = 1.f / fmaxf(dsum, 1e-16f);
        u16 bu[8];
        *(uint4*)bu = *(const uint4*)(bias + hl * 8);
        float v[8];
#pragma unroll
        for (int p = 0; p < 4; p++) {
            float x0 = acc2[p].x * inv + b2f(bu[2 * p]);
            float x1 = acc2[p].y * inv + b2f(bu[2 * p + 1]);
            v[2 * p]     = 0.5f * x0 * (1.f + erff(x0 * 0.70710678118654752f));
            v[2 * p + 1] = 0.5f * x1 * (1.f + erff(x1 * 0.70710678118654752f));
        }
        uint4 o;
        o.x = cvtpk(v[0], v[1]); o.y = cvtpk(v[2], v[3]);
        o.z = cvtpk(v[4], v[5]); o.w = cvtpk(v[6], v[7]);
        *(uint4*)(hout + (size_t)n * JH1 + hl * 8) = o;
    }
}

// ---------------------------------------------------------------------------
// Layer-2 aggregate (R13): one wave per dst node, 4 edges in flight
// (16-lane group per edge, 2 ch/lane), 16-deep main loop, abs-form leaky.
// ---------------------------------------------------------------------------
__global__ __launch_bounds__(256) void agg2(
    const u16* __restrict__ Y2, const int* __restrict__ rowptr,
    const int* __restrict__ col, const u16* __restrict__ att,
    const u16* __restrict__ bias, void* __restrict__ dout, int NN,
    const int* __restrict__ flag) {
    const int wid = blockIdx.x * 4 + (threadIdx.x >> 6);
    if (wid >= NN) return;
    const int lane = threadIdx.x & 63, le = lane >> 4, cl = lane & 15;
    const int n = wid;

    f32x2 xr2 = unpk(*(const unsigned*)(Y2 + (size_t)n * JT2 + JH2 + cl * 2));
    f32x2 av  = unpk(*(const unsigned*)(att + cl * 2));
    f32x2 a06; a06.x = 0.6f * av.x; a06.y = 0.6f * av.y;
    f32x2 a04; a04.x = 0.4f * av.x; a04.y = 0.4f * av.y;
    f32x2 acc2 = {0.f, 0.f};
    float dsum = 0.f;

    auto edge = [&](unsigned raw, bool act) {
        f32x2 xl2 = unpk(raw);
        f32x2 z = pk_add(xl2, xr2);
        f32x2 p2 = pk_fma(z, a06, (f32x2){0.f, 0.f});
        p2 = pk_fma(pabs(z), a04, p2);
        float pl = p2.x + p2.y;
        pl += __shfl_xor(pl, 1); pl += __shfl_xor(pl, 2);
        pl += __shfl_xor(pl, 4); pl += __shfl_xor(pl, 8);
        float e = __expf(pl);
        if (!act) e = 0.f;
        dsum += e;
        f32x2 e2; e2.x = e; e2.y = e;
        acc2 = pk_fma(e2, xl2, acc2);
    };

    const int beg = rowptr[n], end = rowptr[n + 1];
    int i = beg;
    for (; i + 16 <= end; i += 16) {
        int s0 = col[i + le], s1 = col[i + 4 + le];
        int s2 = col[i + 8 + le], s3 = col[i + 12 + le];
        unsigned r0 = *(const unsigned*)(Y2 + (size_t)s0 * JT2 + cl * 2);
        unsigned r1 = *(const unsigned*)(Y2 + (size_t)s1 * JT2 + cl * 2);
        unsigned r2 = *(const unsigned*)(Y2 + (size_t)s2 * JT2 + cl * 2);
        unsigned r3 = *(const unsigned*)(Y2 + (size_t)s3 * JT2 + cl * 2);
        edge(r0, true); edge(r1, true); edge(r2, true); edge(r3, true);
    }
    for (; i + 8 <= end; i += 8) {
        int sA = col[i + le];
        int sB = col[i + 4 + le];
        unsigned rA = *(const unsigned*)(Y2 + (size_t)sA * JT2 + cl * 2);
        unsigned rB = *(const unsigned*)(Y2 + (size_t)sB * JT2 + cl * 2);
        edge(rA, true);
        edge(rB, true);
    }
    for (; i < end; i += 4) {
        int idx = i + le;
        bool act = idx < end;
        int s0 = col[act ? idx : end - 1];
        unsigned r0 = *(const unsigned*)(Y2 + (size_t)s0 * JT2 + cl * 2);
        edge(r0, act);
    }

    dsum += __shfl_xor(dsum, 16); dsum += __shfl_xor(dsum, 32);
    acc2.x += __shfl_xor(acc2.x, 16); acc2.x += __shfl_xor(acc2.x, 32);
    acc2.y += __shfl_xor(acc2.y, 16); acc2.y += __shfl_xor(acc2.y, 32);

    if (le == 0) {
        float inv = 1.f / fmaxf(dsum, 1e-16f);
        f32x2 bv = unpk(*(const unsigned*)(bias + cl * 2));
        float v0 = acc2.x * inv + bv.x;
        float v1 = acc2.y * inv + bv.y;
        if (*flag) {
            *(unsigned*)((u16*)dout + n * JH2 + cl * 2) = cvtpk(v0, v1);
        } else {
            float2 o; o.x = v0; o.y = v1;
            *(float2*)((float*)dout + n * JH2 + cl * 2) = o;
        }
    }
}

extern "C" void kernel_launch(void* const* d_in, const int* in_sizes, int n_in,
                              void* d_out, int out_size, void* d_ws, size_t ws_size,
                              hipStream_t stream) {
    const int NN = in_sizes[0] / F_IN;   // 50000
    const int EE = in_sizes[1] / 2;      // 800000
    const int EP = EE + NN;
    if (ws_size < WS_NEED) return;

    char* w = (char*)d_ws;
    u16*   Y1   = (u16*)(w + OFF_Y1);
    u16*   hbuf = (u16*)(w + OFF_H);
    u16*   Y2   = (u16*)(w + OFF_Y2);
    int*   col  = (int*)(w + OFF_COL);
    int*   deg  = (int*)(w + OFF_DEG);
    int*   rowp = (int*)(w + OFF_ROW);
    int*   cur  = (int*)(w + OFF_CUR);
    u16*   Wc   = (u16*)(w + OFF_WC);
    int*   flag = (int*)(w + OFF_FLAG);
    int*   bsum = (int*)(w + OFF_BSUM);

    const int* ei = (const int*)d_in[1];

    // 1) zero deg, then fused weights-cvt + degree histogram
    hipMemsetAsync(deg, 0, (size_t)NN * 4, stream);
    {
        WcArgs a;
        int sizes[12] = {JH1 * F_IN, JH1, JH1 * F_IN, JH1, H1 * CH, JH1,
                         JH2 * JH1, JH2, JH2 * JH1, JH2, JH2, JH2};
        int c = 0;
        for (int s = 0; s < 12; s++) { a.src[s] = d_in[2 + s]; a.cum[s] = c; c += sizes[s]; }
        a.cum[12] = c;
        const int NBW = (W_TOTAL + 255) / 256;
        const int NBE = (EP + 255) / 256;
        prep<<<NBW + NBE, 256, 0, stream>>>(a, (const u16*)d_in[0], Wc, W_TOTAL,
                                            flag, NBW, ei, deg, EE, NN);
    }

    // 2) CSR scan
    const int NB = (NN + 1023) / 1024;   // 49 (<=256 supported)
    scan_part<<<NB, 256, 0, stream>>>(deg, bsum, NN);
    scan_final<<<NB, 256, 0, stream>>>(deg, bsum, rowp, cur, NN, NB);

    // 3) layer-1 GEMM fused with edge scatter
    {
        const int NBG = (NN + 127) / 128;
        const int NBE = (EP + 255) / 256;
        gemm1_scatter<<<NBG + NBE, 256, 0, stream>>>(
            d_in[0], Wc + W_WL1, Wc + W_WR1, Wc + W_BL1, Wc + W_BR1,
            Y1, NN, flag, NBG, ei, cur, col, EE, NN);
    }
    agg1<<<(NN + 3) / 4, 256, 0, stream>>>(Y1, rowp, col, Wc + W_ATT1,
                                           Wc + W_BIAS1, hbuf, NN);

    // 4) layer 2
    gemm2_k<<<(NN + 127) / 128, 256, 0, stream>>>(
        hbuf, Wc + W_WL2, Wc + W_WR2, Wc + W_BL2, Wc + W_BR2, Y2, NN, flag);
    agg2<<<(NN + 3) / 4, 256, 0, stream>>>(Y2, rowp, col, Wc + W_ATT2,
                                           Wc + W_BIAS2, d_out, NN, flag);
}